// Round 4
// baseline (337.742 us; speedup 1.0000x reference)
//
#include <hip/hip_runtime.h>

// Conv_Attention: q,k,v = causal_conv1d(x, W*) ; S = qk^T/sqrt(U);
// softmax over QUERY axis (per-column of S); out = P @ v.
// B=8, T=2048, Cin=U=512, K=3.
//
// Round 4 structure:
//  1. prep_x: x fp32 -> xpad bf16 [B][T+2][512]  (conv == GEMM: A[m][k]=xpad_flat[m*512+k])
//  2. transpose Wq/Wk/Wv -> Wt_all [1536 u][1536 k] bf16
//  3. ONE QKV GEMM (N=1536) -> QKV bf16 [B][2048][1536]
//  4. transpose V slice -> Vt bf16 [B][512][2048]
//  5. scores GEMM: epilogue computes e = exp(S*scale - 16) (fixed shift, |S|<~25
//     so safe), stores P_raw = bf16(e) AND fuses partial column sums of e.
//     Normalizer folded into V, not P:  ctx = P_raw @ (Vt / L)^T.
//  6. stats_combine: inv[k] = 1 / sum_mb pl[mb][k]
//  7. scale_vt: Vt[d][k] *= inv[k]  (33 MB RW vs the old 268 MB apply_exp)
//  8. ctx GEMM 128x64 tiles (1024 blocks) -> out fp32
//
// GEMM: 128 x (WN*32) tile, 4 waves (2x2), BK=32 (R2-verified: BK=64 cut
// occupancy 29->21% and lost MfmaUtil), global_load_lds width=16 staging,
// XOR chunk swizzle (q ^= (row>>1)&3) => 0 LDS bank conflicts (verified R2/R3).

#define B_   8
#define T_   2048
#define D_   512
#define KC_  1536
#define TPAD_ 2050

using short8  = __attribute__((ext_vector_type(8))) short;
using float4v = __attribute__((ext_vector_type(4))) float;

__device__ __forceinline__ float bf2f(unsigned short b) {
  unsigned u = ((unsigned)b) << 16;
  float f; __builtin_memcpy(&f, &u, 4); return f;
}
__device__ __forceinline__ unsigned short f2bf(float f) {
  unsigned u; __builtin_memcpy(&u, &f, 4);
  u += 0x7fffu + ((u >> 16) & 1u);          // RNE (finite inputs only)
  return (unsigned short)(u >> 16);
}

__device__ __forceinline__ void gld16(const void* g, void* l) {
  __builtin_amdgcn_global_load_lds((__attribute__((address_space(1))) void*)g,
                                   (__attribute__((address_space(3))) void*)l,
                                   16, 0, 0);
}

// ---------------- prep: pad + cast x ----------------
__global__ __launch_bounds__(256) void prep_x(const float* __restrict__ x,
                                              unsigned short* __restrict__ xpad) {
  const int b = blockIdx.y;
  const int i = (blockIdx.x * 256 + threadIdx.x) * 4;   // grid.x=1025 -> exactly 2050*512
  const int t = i >> 9;
  unsigned short* dst = xpad + (size_t)b * (TPAD_ * D_) + i;
  if (t < 2) {
    dst[0] = 0; dst[1] = 0; dst[2] = 0; dst[3] = 0;
  } else {
    const float* sp = x + ((size_t)b * T_ + (t - 2)) * D_ + (i & 511);
    float4v v = *(const float4v*)sp;
    dst[0] = f2bf(v[0]); dst[1] = f2bf(v[1]); dst[2] = f2bf(v[2]); dst[3] = f2bf(v[3]);
  }
}

// ---------------- bias concat ----------------
__global__ __launch_bounds__(256) void concat_bias(const float* __restrict__ bq,
                                                   const float* __restrict__ bk,
                                                   const float* __restrict__ bv,
                                                   float* __restrict__ out) {
  const int i = blockIdx.x * 256 + threadIdx.x;   // grid 6 -> 1536
  float v = (i < 512) ? bq[i] : ((i < 1024) ? bk[i - 512] : bv[i - 1024]);
  out[i] = v;
}

// ---------------- transpose (+cast) to bf16: src [R][C] -> dst [C][R] ----------------
template <typename TI>
__global__ __launch_bounds__(256) void transpose_to_bf16(const TI* __restrict__ src,
                                                         unsigned short* __restrict__ dst,
                                                         int R, int C, int ldSrc, int ldDst,
                                                         long long sSrc, long long sDst) {
  __shared__ unsigned short tile[64][65];
  const TI* s = src + (size_t)blockIdx.z * (size_t)sSrc;
  unsigned short* d = dst + (size_t)blockIdx.z * (size_t)sDst;
  const int r0 = blockIdx.x * 64, c0 = blockIdx.y * 64;
  const int tc = threadIdx.x & 63, tg = threadIdx.x >> 6;
#pragma unroll
  for (int i = 0; i < 16; i++) {
    const int r = i * 4 + tg;
    TI v = s[(size_t)(r0 + r) * ldSrc + (c0 + tc)];
    unsigned short bits;
    if constexpr (sizeof(TI) == 4) bits = f2bf((float)v);
    else                           bits = (unsigned short)v;
    tile[r][tc] = bits;
  }
  __syncthreads();
#pragma unroll
  for (int i = 0; i < 16; i++) {
    const int rr = i * 4 + tg;
    d[(size_t)(c0 + rr) * ldDst + (r0 + tc)] = tile[tc][rr];
  }
}

// ---------------- combine: inv[k] = 1 / sum of partial colsums ----------------
__global__ __launch_bounds__(256) void stats_combine(const float* __restrict__ pl,
                                                     long long sPz,
                                                     float* __restrict__ inv,
                                                     long long sIz) {
  const size_t z = blockIdx.z;
  const int col = blockIdx.x * 256 + threadIdx.x;
  float L = 0.f;
#pragma unroll
  for (int mb = 0; mb < 16; mb++)
    L += pl[z * (size_t)sPz + (size_t)mb * T_ + col];
  inv[z * (size_t)sIz + col] = 1.0f / L;
}

// ---------------- scale Vt rows: Vt[d][k] *= inv[k] ----------------
__global__ __launch_bounds__(256) void scale_vt(unsigned short* __restrict__ Vt,
                                                long long sVz,
                                                const float* __restrict__ inv,
                                                long long sIz) {
  const size_t z = blockIdx.z;
  unsigned short* Vb = Vt + z * (size_t)sVz;
  const float* iv = inv + z * (size_t)sIz;
  const int idx = (blockIdx.x * 256 + threadIdx.x) * 8;  // grid.x=512 -> 512*2048
  const int k = idx & (T_ - 1);
  short8 v = *(const short8*)(Vb + idx);
  float4v i0 = *(const float4v*)(iv + k);
  float4v i1 = *(const float4v*)(iv + k + 4);
  short8 o;
#pragma unroll
  for (int j = 0; j < 8; j++) {
    float s = (j < 4) ? i0[j & 3] : i1[j & 3];
    o[j] = (short)f2bf(bf2f((unsigned short)v[j]) * s);
  }
  *(short8*)(Vb + idx) = o;
}

// ---------------- unified GEMM: C = A * B'^T  (BK=32) ----------------
// A [M][K] bf16 row-major (lda), B' [N][K] bf16 row-major (ldb), k-contiguous.
// MODE 0: bias add, bf16 out                       (QKV conv GEMM, 128x128)
// MODE 1: P_raw = exp(v*scale-16) bf16 out + colsum (scores,       128x128)
// MODE 2: plain, fp32 out                          (ctx,           128x64)
template <int MODE>
__global__ __launch_bounds__(256)
void gemm_bt(const unsigned short* __restrict__ A, long long sAz, int lda,
             const unsigned short* __restrict__ Bm, long long sBz, int ldb,
             void* __restrict__ Out, long long sOz, int ldo,
             const float* __restrict__ bias,
             float* __restrict__ pl, long long sPz,
             int Kdim, float scale) {
  constexpr int WN = (MODE == 2) ? 2 : 4;  // wave n-subtiles (x16 cols)
  constexpr int BN = WN * 32;              // block n-extent
  __shared__ unsigned short At[128 * 32];
  __shared__ unsigned short Bt[BN * 32];
  const int tid = threadIdx.x;
  const int lane = tid & 63;
  const int wave = tid >> 6;
  const int wm = wave >> 1, wn = wave & 1;
  const size_t z = blockIdx.z;
  const unsigned short* Ab = A + z * (size_t)sAz;
  const unsigned short* Bb = Bm + z * (size_t)sBz;
  const int m0 = blockIdx.x * 128, n0 = blockIdx.y * BN;

  float4v acc[4][WN];
#pragma unroll
  for (int i = 0; i < 4; i++)
#pragma unroll
    for (int j = 0; j < WN; j++) acc[i][j] = float4v{0.f, 0.f, 0.f, 0.f};

  // staging lane map: lane -> row rloc=lane>>2 (of 16), stored chunk qs=lane&3,
  // fetched global chunk = qs ^ ((row>>1)&3)  (rows r, r+16 share the swizzle).
  const int rloc = lane >> 2, qs = lane & 3;
  const int rA = wave * 32 + rloc;
  const int qgA = qs ^ ((rA >> 1) & 3);
  const unsigned short* gA0 = Ab + (size_t)(m0 + rA) * lda + qgA * 8;
  const unsigned short* gA1 = gA0 + (size_t)16 * lda;
  unsigned short* lA0 = At + wave * 1024;
  unsigned short* lA1 = lA0 + 512;

  const int rB = (WN == 4) ? (wave * 32 + rloc) : (wave * 16 + rloc);
  const int qgB = qs ^ ((rB >> 1) & 3);
  const unsigned short* gB0 = Bb + (size_t)(n0 + rB) * ldb + qgB * 8;
  const unsigned short* gB1 = gB0 + (size_t)16 * ldb;   // WN==4 only
  unsigned short* lB0 = Bt + ((WN == 4) ? wave * 1024 : wave * 512);
  unsigned short* lB1 = lB0 + 512;

  // fragment read addressing (same XOR swizzle)
  const int cl = lane & 15;
  const int qd = lane >> 4;
  const int arow = wm * 64 + cl;
  const int qa = qd ^ ((arow >> 1) & 3);
  const int brow = wn * (WN * 16) + cl;
  const int qb = qd ^ ((brow >> 1) & 3);

  for (int kk = 0; kk < Kdim; kk += 32) {
    gld16(gA0, lA0);
    gld16(gA1, lA1);
    gld16(gB0, lB0);
    if constexpr (WN == 4) gld16(gB1, lB1);
    __syncthreads();

    short8 af[4], bfr[WN];
#pragma unroll
    for (int i = 0; i < 4; i++)
      af[i] = *(const short8*)&At[(arow + i * 16) * 32 + qa * 8];
#pragma unroll
    for (int j = 0; j < WN; j++)
      bfr[j] = *(const short8*)&Bt[(brow + j * 16) * 32 + qb * 8];
#pragma unroll
    for (int i = 0; i < 4; i++)
#pragma unroll
      for (int j = 0; j < WN; j++)
        acc[i][j] = __builtin_amdgcn_mfma_f32_16x16x32_bf16(af[i], bfr[j], acc[i][j], 0, 0, 0);
    __syncthreads();

    gA0 += 32; gA1 += 32; gB0 += 32;
    if constexpr (WN == 4) gB1 += 32;
  }

  // epilogue: C[row=(lane>>4)*4+r][col=lane&15] per 16x16 subtile
  float cs[WN];
#pragma unroll
  for (int j = 0; j < WN; j++) cs[j] = 0.f;
#pragma unroll
  for (int i = 0; i < 4; i++) {
    const int row = m0 + wm * 64 + i * 16 + qd * 4;
#pragma unroll
    for (int j = 0; j < WN; j++) {
      const int col = n0 + wn * (WN * 16) + j * 16 + cl;
      float badd = 0.f;
      if constexpr (MODE == 0) badd = bias[col];
#pragma unroll
      for (int r = 0; r < 4; r++) {
        float v = acc[i][j][r] * scale + badd;
        if constexpr (MODE == 2) {
          ((float*)Out)[z * (size_t)sOz + (size_t)(row + r) * ldo + col] = v;
        } else if constexpr (MODE == 1) {
          float e = __expf(v - 16.f);          // fixed shift; |v| <~ 25
          cs[j] += e;
          ((unsigned short*)Out)[z * (size_t)sOz + (size_t)(row + r) * ldo + col] = f2bf(e);
        } else {
          ((unsigned short*)Out)[z * (size_t)sOz + (size_t)(row + r) * ldo + col] = f2bf(v);
        }
      }
    }
  }
  if constexpr (MODE == 1) {
    // reduce over rows: qd groups via shuffle, wm pair via LDS (At is free now)
#pragma unroll
    for (int j = 0; j < 4; j++) {
      cs[j] += __shfl_xor(cs[j], 16, 64);
      cs[j] += __shfl_xor(cs[j], 32, 64);
    }
    float* red = (float*)At;
    if (wm == 1 && qd == 0) {
#pragma unroll
      for (int j = 0; j < 4; j++) red[wn * 64 + j * 16 + cl] = cs[j];
    }
    __syncthreads();
    if (wm == 0 && qd == 0) {
#pragma unroll
      for (int j = 0; j < 4; j++) {
        const int c = wn * 64 + j * 16 + cl;
        pl[z * (size_t)sPz + (size_t)blockIdx.x * T_ + (n0 + c)] = cs[j] + red[c];
      }
    }
  }
}

// ---------------- host ----------------
extern "C" void kernel_launch(void* const* d_in, const int* in_sizes, int n_in,
                              void* d_out, int out_size, void* d_ws, size_t ws_size,
                              hipStream_t stream) {
  const float* x  = (const float*)d_in[0];
  const float* Wq = (const float*)d_in[1];
  const float* bq = (const float*)d_in[2];
  const float* Wk = (const float*)d_in[3];
  const float* bk = (const float*)d_in[4];
  const float* Wv = (const float*)d_in[5];
  const float* bv = (const float*)d_in[6];

  char* ws = (char*)d_ws;
  auto alloc = [&](size_t bytes) {
    char* p = ws; ws += (bytes + 255) & ~(size_t)255; return p;
  };
  unsigned short* xpad = (unsigned short*)alloc((size_t)B_ * TPAD_ * D_ * 2);
  unsigned short* Wt   = (unsigned short*)alloc((size_t)KC_ * KC_ * 2);     // [1536 u][1536 k]
  float*          bcat = (float*)alloc((size_t)KC_ * 4);
  unsigned short* QKV  = (unsigned short*)alloc((size_t)B_ * T_ * KC_ * 2); // [B][T][1536]
  unsigned short* Vt   = (unsigned short*)alloc((size_t)B_ * D_ * T_ * 2);
  float* invb = (float*)alloc((size_t)B_ * T_ * 4);
  float* pl   = (float*)alloc((size_t)B_ * 16 * T_ * 4);
  size_t used = (size_t)(ws - (char*)d_ws);
  const size_t sAll = (size_t)B_ * T_ * T_ * 2;   // bf16 P, all batches
  const size_t sOne = (size_t)T_ * T_ * 2;
  const int NB = (used + sAll <= ws_size) ? B_ : 1;  // ws-adaptive batching
  unsigned short* Sb = (unsigned short*)alloc(NB == B_ ? sAll : sOne);

  prep_x<<<dim3(1025, B_), 256, 0, stream>>>(x, xpad);
  concat_bias<<<dim3(6), 256, 0, stream>>>(bq, bk, bv, bcat);

  // Wq/Wk/Wv [1536][512] fp32 -> Wt rows [w*512 .. w*512+511], row length 1536
  const float* Ws[3] = {Wq, Wk, Wv};
  for (int w = 0; w < 3; w++)
    transpose_to_bf16<float><<<dim3(24, 8, 1), 256, 0, stream>>>(
        Ws[w], Wt + (size_t)w * D_ * KC_, KC_, D_, D_, KC_, 0, 0);

  // one QKV GEMM: M=2048/batch, N=1536, K=1536
  gemm_bt<0><<<dim3(16, 12, B_), 256, 0, stream>>>(
      xpad, (long long)TPAD_ * D_, D_,
      Wt, 0, KC_,
      QKV, (long long)T_ * KC_, KC_,
      bcat, nullptr, 0, KC_, 1.0f);

  // V slice [T][512] (row stride 1536) -> Vt [512][2048]
  transpose_to_bf16<unsigned short><<<dim3(32, 8, B_), 256, 0, stream>>>(
      QKV + 2 * D_, Vt, T_, D_, KC_, T_,
      (long long)T_ * KC_, (long long)D_ * T_);

  const float scale = 0.044194173824159216f;  // 1/sqrt(512)
  for (int b0 = 0; b0 < B_; b0 += NB) {
    const unsigned short* Qp = QKV + (size_t)b0 * T_ * KC_;          // +0
    const unsigned short* Kp = QKV + (size_t)b0 * T_ * KC_ + D_;     // +512
    // P_raw = exp(S-16) + partial column sums
    gemm_bt<1><<<dim3(16, 16, NB), 256, 0, stream>>>(
        Qp, (long long)T_ * KC_, KC_,
        Kp, (long long)T_ * KC_, KC_,
        Sb, (long long)T_ * T_, T_,
        nullptr, pl + (size_t)b0 * 16 * T_, (long long)16 * T_,
        D_, scale);
    stats_combine<<<dim3(8, 1, NB), 256, 0, stream>>>(
        pl + (size_t)b0 * 16 * T_, (long long)16 * T_,
        invb + (size_t)b0 * T_, T_);
    scale_vt<<<dim3(512, 1, NB), 256, 0, stream>>>(
        Vt + (size_t)b0 * D_ * T_, (long long)D_ * T_,
        invb + (size_t)b0 * T_, T_);
    gemm_bt<2><<<dim3(16, 8, NB), 256, 0, stream>>>(
        Sb, (long long)T_ * T_, T_,
        Vt + (size_t)b0 * D_ * T_, (long long)D_ * T_, T_,
        (float*)d_out + (size_t)b0 * T_ * D_, (long long)T_ * D_, D_,
        nullptr, nullptr, 0, T_, 1.0f);
  }
}

// Round 5
// 327.908 us; speedup vs baseline: 1.0300x; 1.0300x over previous
//
#include <hip/hip_runtime.h>

// Conv_Attention: q,k,v = causal_conv1d(x, W*) ; S = qk^T/sqrt(U);
// softmax over QUERY axis (per-column of S); out = P @ v.
// B=8, T=2048, Cin=U=512, K=3.
//
// Round 5 structure (R4 pipeline, GEMM core moved to 32x32x16 MFMA):
//  1. prep_x: x fp32 -> xpad bf16 [B][T+2][512]  (conv == GEMM)
//  2. transpose Wq/Wk/Wv -> Wt_all [1536 u][1536 k] bf16
//  3. ONE QKV GEMM (N=1536) -> QKV bf16 [B][2048][1536]
//  4. transpose V slice -> Vt bf16 [B][512][2048]
//  5. scores GEMM: epilogue stores P_raw = bf16(exp(S*scale-16)) + partial colsums
//  6. stats_combine: inv[k] = 1/L[k]
//  7. scale_vt: Vt[d][k] *= inv[k]
//  8. ctx GEMM 128x64 tiles -> out fp32
//
// GEMM: 128 x BN tile, 4 waves (2x2), each wave 64 x (NJ*32) via 32x32x16
// MFMAs (2382 TF ceiling vs 2075 for 16x16x32; half the instruction count).
// BK=32, global_load_lds width=16 staging, XOR chunk swizzle (q ^= (row>>1)&3)
// => 0 LDS bank conflicts (verified R2-R4 for the same store/read family).
// 32x32x16 layouts (m74/m101 HW-verified): C/D col=lane&31,
// row=(reg&3)+8*(reg>>2)+4*(lane>>5); A/B [lane&31][k=(lane>>5)*8+j].

#define B_   8
#define T_   2048
#define D_   512
#define KC_  1536
#define TPAD_ 2050

using short8   = __attribute__((ext_vector_type(8))) short;
using float4v  = __attribute__((ext_vector_type(4))) float;
using float16v = __attribute__((ext_vector_type(16))) float;

__device__ __forceinline__ float bf2f(unsigned short b) {
  unsigned u = ((unsigned)b) << 16;
  float f; __builtin_memcpy(&f, &u, 4); return f;
}
__device__ __forceinline__ unsigned short f2bf(float f) {
  unsigned u; __builtin_memcpy(&u, &f, 4);
  u += 0x7fffu + ((u >> 16) & 1u);          // RNE (finite inputs only)
  return (unsigned short)(u >> 16);
}

__device__ __forceinline__ void gld16(const void* g, void* l) {
  __builtin_amdgcn_global_load_lds((__attribute__((address_space(1))) void*)g,
                                   (__attribute__((address_space(3))) void*)l,
                                   16, 0, 0);
}

// ---------------- prep: pad + cast x ----------------
__global__ __launch_bounds__(256) void prep_x(const float* __restrict__ x,
                                              unsigned short* __restrict__ xpad) {
  const int b = blockIdx.y;
  const int i = (blockIdx.x * 256 + threadIdx.x) * 4;   // grid.x=1025 -> exactly 2050*512
  const int t = i >> 9;
  unsigned short* dst = xpad + (size_t)b * (TPAD_ * D_) + i;
  if (t < 2) {
    dst[0] = 0; dst[1] = 0; dst[2] = 0; dst[3] = 0;
  } else {
    const float* sp = x + ((size_t)b * T_ + (t - 2)) * D_ + (i & 511);
    float4v v = *(const float4v*)sp;
    dst[0] = f2bf(v[0]); dst[1] = f2bf(v[1]); dst[2] = f2bf(v[2]); dst[3] = f2bf(v[3]);
  }
}

// ---------------- bias concat ----------------
__global__ __launch_bounds__(256) void concat_bias(const float* __restrict__ bq,
                                                   const float* __restrict__ bk,
                                                   const float* __restrict__ bv,
                                                   float* __restrict__ out) {
  const int i = blockIdx.x * 256 + threadIdx.x;   // grid 6 -> 1536
  float v = (i < 512) ? bq[i] : ((i < 1024) ? bk[i - 512] : bv[i - 1024]);
  out[i] = v;
}

// ---------------- transpose (+cast) to bf16: src [R][C] -> dst [C][R] ----------------
template <typename TI>
__global__ __launch_bounds__(256) void transpose_to_bf16(const TI* __restrict__ src,
                                                         unsigned short* __restrict__ dst,
                                                         int R, int C, int ldSrc, int ldDst,
                                                         long long sSrc, long long sDst) {
  __shared__ unsigned short tile[64][65];
  const TI* s = src + (size_t)blockIdx.z * (size_t)sSrc;
  unsigned short* d = dst + (size_t)blockIdx.z * (size_t)sDst;
  const int r0 = blockIdx.x * 64, c0 = blockIdx.y * 64;
  const int tc = threadIdx.x & 63, tg = threadIdx.x >> 6;
#pragma unroll
  for (int i = 0; i < 16; i++) {
    const int r = i * 4 + tg;
    TI v = s[(size_t)(r0 + r) * ldSrc + (c0 + tc)];
    unsigned short bits;
    if constexpr (sizeof(TI) == 4) bits = f2bf((float)v);
    else                           bits = (unsigned short)v;
    tile[r][tc] = bits;
  }
  __syncthreads();
#pragma unroll
  for (int i = 0; i < 16; i++) {
    const int rr = i * 4 + tg;
    d[(size_t)(c0 + rr) * ldDst + (r0 + tc)] = tile[tc][rr];
  }
}

// ---------------- combine: inv[k] = 1 / sum of partial colsums ----------------
__global__ __launch_bounds__(256) void stats_combine(const float* __restrict__ pl,
                                                     long long sPz,
                                                     float* __restrict__ inv,
                                                     long long sIz) {
  const size_t z = blockIdx.z;
  const int col = blockIdx.x * 256 + threadIdx.x;
  float L = 0.f;
#pragma unroll
  for (int mb = 0; mb < 16; mb++)
    L += pl[z * (size_t)sPz + (size_t)mb * T_ + col];
  inv[z * (size_t)sIz + col] = 1.0f / L;
}

// ---------------- scale Vt rows: Vt[d][k] *= inv[k] ----------------
__global__ __launch_bounds__(256) void scale_vt(unsigned short* __restrict__ Vt,
                                                long long sVz,
                                                const float* __restrict__ inv,
                                                long long sIz) {
  const size_t z = blockIdx.z;
  unsigned short* Vb = Vt + z * (size_t)sVz;
  const float* iv = inv + z * (size_t)sIz;
  const int idx = (blockIdx.x * 256 + threadIdx.x) * 8;  // grid.x=512 -> 512*2048
  const int k = idx & (T_ - 1);
  short8 v = *(const short8*)(Vb + idx);
  float4v i0 = *(const float4v*)(iv + k);
  float4v i1 = *(const float4v*)(iv + k + 4);
  short8 o;
#pragma unroll
  for (int j = 0; j < 8; j++) {
    float s = (j < 4) ? i0[j & 3] : i1[j & 3];
    o[j] = (short)f2bf(bf2f((unsigned short)v[j]) * s);
  }
  *(short8*)(Vb + idx) = o;
}

// ---------------- unified GEMM: C = A * B'^T  (BK=32, 32x32x16 MFMA) ----------------
// A [M][K] bf16 row-major (lda), B' [N][K] bf16 row-major (ldb), k-contiguous.
// MODE 0: bias add, bf16 out                        (QKV conv GEMM, 128x128)
// MODE 1: P_raw = exp(v*scale-16) bf16 out + colsum (scores,        128x128)
// MODE 2: plain, fp32 out                           (ctx,           128x64)
template <int MODE>
__global__ __launch_bounds__(256)
void gemm_bt(const unsigned short* __restrict__ A, long long sAz, int lda,
             const unsigned short* __restrict__ Bm, long long sBz, int ldb,
             void* __restrict__ Out, long long sOz, int ldo,
             const float* __restrict__ bias,
             float* __restrict__ pl, long long sPz,
             int Kdim, float scale) {
  constexpr int NJ = (MODE == 2) ? 1 : 2;  // 32-col subtiles per wave
  constexpr int BN = NJ * 64;              // block n-extent
  __shared__ unsigned short At[128 * 32];
  __shared__ unsigned short Bt[BN * 32];
  const int tid = threadIdx.x;
  const int lane = tid & 63;
  const int wave = tid >> 6;
  const int wm = wave >> 1, wn = wave & 1;
  const size_t z = blockIdx.z;
  const unsigned short* Ab = A + z * (size_t)sAz;
  const unsigned short* Bb = Bm + z * (size_t)sBz;
  const int m0 = blockIdx.x * 128, n0 = blockIdx.y * BN;

  float16v acc[2][NJ];
#pragma unroll
  for (int mi = 0; mi < 2; mi++)
#pragma unroll
    for (int nj = 0; nj < NJ; nj++)
#pragma unroll
      for (int r = 0; r < 16; r++) acc[mi][nj][r] = 0.f;

  // staging lane map: lane -> row rloc=lane>>2 (of 16), stored chunk qs=lane&3,
  // fetched global chunk = qs ^ ((row>>1)&3)  (rows r, r+16 share the swizzle).
  const int rloc = lane >> 2, qs = lane & 3;
  const int rA = wave * 32 + rloc;
  const int qgA = qs ^ ((rA >> 1) & 3);
  const unsigned short* gA0 = Ab + (size_t)(m0 + rA) * lda + qgA * 8;
  const unsigned short* gA1 = gA0 + (size_t)16 * lda;
  unsigned short* lA0 = At + wave * 1024;
  unsigned short* lA1 = lA0 + 512;

  const int rB = (BN == 128) ? (wave * 32 + rloc) : (wave * 16 + rloc);
  const int qgB = qs ^ ((rB >> 1) & 3);
  const unsigned short* gB0 = Bb + (size_t)(n0 + rB) * ldb + qgB * 8;
  const unsigned short* gB1 = gB0 + (size_t)16 * ldb;   // BN==128 only
  unsigned short* lB0 = Bt + ((BN == 128) ? wave * 1024 : wave * 512);
  unsigned short* lB1 = lB0 + 512;

  // fragment read addressing: A/B operand [row = lane&31][k = (lane>>5)*8 + j]
  const int l31 = lane & 31;
  const int hi  = lane >> 5;
  int ar[2], br[NJ];
#pragma unroll
  for (int mi = 0; mi < 2; mi++) ar[mi] = wm * 64 + mi * 32 + l31;
#pragma unroll
  for (int nj = 0; nj < NJ; nj++) br[nj] = wn * (NJ * 32) + nj * 32 + l31;

  for (int kk = 0; kk < Kdim; kk += 32) {
    gld16(gA0, lA0);
    gld16(gA1, lA1);
    gld16(gB0, lB0);
    if constexpr (BN == 128) gld16(gB1, lB1);
    __syncthreads();

    short8 af[2][2], bfr[NJ][2];
#pragma unroll
    for (int h = 0; h < 2; h++) {
      const int qlog = h * 2 + hi;
#pragma unroll
      for (int mi = 0; mi < 2; mi++) {
        const int q = qlog ^ ((ar[mi] >> 1) & 3);
        af[mi][h] = *(const short8*)&At[ar[mi] * 32 + q * 8];
      }
#pragma unroll
      for (int nj = 0; nj < NJ; nj++) {
        const int q = qlog ^ ((br[nj] >> 1) & 3);
        bfr[nj][h] = *(const short8*)&Bt[br[nj] * 32 + q * 8];
      }
    }
#pragma unroll
    for (int h = 0; h < 2; h++)
#pragma unroll
      for (int mi = 0; mi < 2; mi++)
#pragma unroll
        for (int nj = 0; nj < NJ; nj++)
          acc[mi][nj] = __builtin_amdgcn_mfma_f32_32x32x16_bf16(
              af[mi][h], bfr[nj][h], acc[mi][nj], 0, 0, 0);
    __syncthreads();

    gA0 += 32; gA1 += 32; gB0 += 32;
    if constexpr (BN == 128) gB1 += 32;
  }

  // epilogue: C/D col = lane&31, row = (reg&3) + 8*(reg>>2) + 4*(lane>>5)
  float cs[NJ];
#pragma unroll
  for (int nj = 0; nj < NJ; nj++) cs[nj] = 0.f;
#pragma unroll
  for (int mi = 0; mi < 2; mi++) {
#pragma unroll
    for (int nj = 0; nj < NJ; nj++) {
      const int col = n0 + wn * (NJ * 32) + nj * 32 + l31;
      float badd = 0.f;
      if constexpr (MODE == 0) badd = bias[col];
#pragma unroll
      for (int reg = 0; reg < 16; reg++) {
        const int row = m0 + wm * 64 + mi * 32 + (reg & 3) + 8 * (reg >> 2) + 4 * hi;
        float v = acc[mi][nj][reg] * scale + badd;
        if constexpr (MODE == 2) {
          ((float*)Out)[z * (size_t)sOz + (size_t)row * ldo + col] = v;
        } else if constexpr (MODE == 1) {
          float e = __expf(v - 16.f);          // fixed shift; |v| <~ 25
          cs[nj] += e;
          ((unsigned short*)Out)[z * (size_t)sOz + (size_t)row * ldo + col] = f2bf(e);
        } else {
          ((unsigned short*)Out)[z * (size_t)sOz + (size_t)row * ldo + col] = f2bf(v);
        }
      }
    }
  }
  if constexpr (MODE == 1) {
    // column sums: lane & lane^32 cover all 32 rows of a subtile -> xor-32;
    // then reduce the wm pair via LDS (At is free now).
#pragma unroll
    for (int nj = 0; nj < NJ; nj++) cs[nj] += __shfl_xor(cs[nj], 32, 64);
    float* red = (float*)At;
    if (wm == 1 && hi == 0) {
#pragma unroll
      for (int nj = 0; nj < NJ; nj++) red[wn * 64 + nj * 32 + l31] = cs[nj];
    }
    __syncthreads();
    if (wm == 0 && hi == 0) {
#pragma unroll
      for (int nj = 0; nj < NJ; nj++) {
        const int c = wn * 64 + nj * 32 + l31;
        pl[z * (size_t)sPz + (size_t)blockIdx.x * T_ + (n0 + c)] = cs[nj] + red[c];
      }
    }
  }
}

// ---------------- host ----------------
extern "C" void kernel_launch(void* const* d_in, const int* in_sizes, int n_in,
                              void* d_out, int out_size, void* d_ws, size_t ws_size,
                              hipStream_t stream) {
  const float* x  = (const float*)d_in[0];
  const float* Wq = (const float*)d_in[1];
  const float* bq = (const float*)d_in[2];
  const float* Wk = (const float*)d_in[3];
  const float* bk = (const float*)d_in[4];
  const float* Wv = (const float*)d_in[5];
  const float* bv = (const float*)d_in[6];

  char* ws = (char*)d_ws;
  auto alloc = [&](size_t bytes) {
    char* p = ws; ws += (bytes + 255) & ~(size_t)255; return p;
  };
  unsigned short* xpad = (unsigned short*)alloc((size_t)B_ * TPAD_ * D_ * 2);
  unsigned short* Wt   = (unsigned short*)alloc((size_t)KC_ * KC_ * 2);     // [1536 u][1536 k]
  float*          bcat = (float*)alloc((size_t)KC_ * 4);
  unsigned short* QKV  = (unsigned short*)alloc((size_t)B_ * T_ * KC_ * 2); // [B][T][1536]
  unsigned short* Vt   = (unsigned short*)alloc((size_t)B_ * D_ * T_ * 2);
  float* invb = (float*)alloc((size_t)B_ * T_ * 4);
  float* pl   = (float*)alloc((size_t)B_ * 16 * T_ * 4);
  size_t used = (size_t)(ws - (char*)d_ws);
  const size_t sAll = (size_t)B_ * T_ * T_ * 2;   // bf16 P, all batches
  const size_t sOne = (size_t)T_ * T_ * 2;
  const int NB = (used + sAll <= ws_size) ? B_ : 1;  // ws-adaptive batching
  unsigned short* Sb = (unsigned short*)alloc(NB == B_ ? sAll : sOne);

  prep_x<<<dim3(1025, B_), 256, 0, stream>>>(x, xpad);
  concat_bias<<<dim3(6), 256, 0, stream>>>(bq, bk, bv, bcat);

  // Wq/Wk/Wv [1536][512] fp32 -> Wt rows [w*512 .. w*512+511], row length 1536
  const float* Ws[3] = {Wq, Wk, Wv};
  for (int w = 0; w < 3; w++)
    transpose_to_bf16<float><<<dim3(24, 8, 1), 256, 0, stream>>>(
        Ws[w], Wt + (size_t)w * D_ * KC_, KC_, D_, D_, KC_, 0, 0);

  // one QKV GEMM: M=2048/batch, N=1536, K=1536
  gemm_bt<0><<<dim3(16, 12, B_), 256, 0, stream>>>(
      xpad, (long long)TPAD_ * D_, D_,
      Wt, 0, KC_,
      QKV, (long long)T_ * KC_, KC_,
      bcat, nullptr, 0, KC_, 1.0f);

  // V slice [T][512] (row stride 1536) -> Vt [512][2048]
  transpose_to_bf16<unsigned short><<<dim3(32, 8, B_), 256, 0, stream>>>(
      QKV + 2 * D_, Vt, T_, D_, KC_, T_,
      (long long)T_ * KC_, (long long)D_ * T_);

  const float scale = 0.044194173824159216f;  // 1/sqrt(512)
  for (int b0 = 0; b0 < B_; b0 += NB) {
    const unsigned short* Qp = QKV + (size_t)b0 * T_ * KC_;          // +0
    const unsigned short* Kp = QKV + (size_t)b0 * T_ * KC_ + D_;     // +512
    // P_raw = exp(S-16) + partial column sums
    gemm_bt<1><<<dim3(16, 16, NB), 256, 0, stream>>>(
        Qp, (long long)T_ * KC_, KC_,
        Kp, (long long)T_ * KC_, KC_,
        Sb, (long long)T_ * T_, T_,
        nullptr, pl + (size_t)b0 * 16 * T_, (long long)16 * T_,
        D_, scale);
    stats_combine<<<dim3(8, 1, NB), 256, 0, stream>>>(
        pl + (size_t)b0 * 16 * T_, (long long)16 * T_,
        invb + (size_t)b0 * T_, T_);
    scale_vt<<<dim3(512, 1, NB), 256, 0, stream>>>(
        Vt + (size_t)b0 * D_ * T_, (long long)D_ * T_,
        invb + (size_t)b0 * T_, T_);
    gemm_bt<2><<<dim3(16, 8, NB), 256, 0, stream>>>(
        Sb, (long long)T_ * T_, T_,
        Vt + (size_t)b0 * D_ * T_, (long long)D_ * T_, T_,
        (float*)d_out + (size_t)b0 * T_ * D_, (long long)T_ * D_, D_,
        nullptr, nullptr, 0, T_, 1.0f);
  }
}

// Round 6
// 324.039 us; speedup vs baseline: 1.0423x; 1.0119x over previous
//
#include <hip/hip_runtime.h>

// Conv_Attention: q,k,v = causal_conv1d(x, W*) ; S = qk^T/sqrt(U);
// softmax over QUERY axis (per-column of S); out = P @ v.
// B=8, T=2048, Cin=U=512, K=3.
//
// Round 6 structure (R5 pipeline; GEMM occupancy push):
//  1. prep_x: x fp32 -> xpad bf16 [B][T+2][512]  (conv == GEMM)
//  2. transpose Wq/Wk/Wv -> Wt_all [1536 u][1536 k] bf16
//  3. ONE QKV GEMM (N=1536) -> QKV bf16 [B][2048][1536]
//  4. transpose V slice -> Vt bf16 [B][512][2048]
//  5. scores GEMM: epilogue stores P_raw = bf16(exp(S*scale-16)) + partial colsums
//  6. stats_combine: inv[k] = 1/L[k]
//  7. scale_vt: Vt[d][k] *= inv[k]
//  8. ctx GEMM 128x128 tiles -> out fp32   (R5 was 128x64: ~805 MB tiled reads;
//     128x128 halves A(P) re-reads to ~537 MB)
//
// GEMM: 128x128 tile, 4 waves (2x2), wave = 64x64 via 32x32x16 MFMAs, BK=32,
// global_load_lds width=16 staging, XOR chunk swizzle (q ^= (row>>1)&3).
// __launch_bounds__(256,4): R5 ran at 30% occupancy (3 waves/SIMD) because
// 64 AGPR acc + frags pushed unified VGPR+AGPR ~148; forcing <=128 gives
// 4 waves/SIMD — the latency-bound K-loop (MFMA 29%/VALU 13%/HBM 11%) needs TLP.

#define B_   8
#define T_   2048
#define D_   512
#define KC_  1536
#define TPAD_ 2050

using short8   = __attribute__((ext_vector_type(8))) short;
using float4v  = __attribute__((ext_vector_type(4))) float;
using float16v = __attribute__((ext_vector_type(16))) float;

__device__ __forceinline__ float bf2f(unsigned short b) {
  unsigned u = ((unsigned)b) << 16;
  float f; __builtin_memcpy(&f, &u, 4); return f;
}
__device__ __forceinline__ unsigned short f2bf(float f) {
  unsigned u; __builtin_memcpy(&u, &f, 4);
  u += 0x7fffu + ((u >> 16) & 1u);          // RNE (finite inputs only)
  return (unsigned short)(u >> 16);
}

__device__ __forceinline__ void gld16(const void* g, void* l) {
  __builtin_amdgcn_global_load_lds((__attribute__((address_space(1))) void*)g,
                                   (__attribute__((address_space(3))) void*)l,
                                   16, 0, 0);
}

// ---------------- prep: pad + cast x ----------------
__global__ __launch_bounds__(256) void prep_x(const float* __restrict__ x,
                                              unsigned short* __restrict__ xpad) {
  const int b = blockIdx.y;
  const int i = (blockIdx.x * 256 + threadIdx.x) * 4;   // grid.x=1025 -> exactly 2050*512
  const int t = i >> 9;
  unsigned short* dst = xpad + (size_t)b * (TPAD_ * D_) + i;
  if (t < 2) {
    dst[0] = 0; dst[1] = 0; dst[2] = 0; dst[3] = 0;
  } else {
    const float* sp = x + ((size_t)b * T_ + (t - 2)) * D_ + (i & 511);
    float4v v = *(const float4v*)sp;
    dst[0] = f2bf(v[0]); dst[1] = f2bf(v[1]); dst[2] = f2bf(v[2]); dst[3] = f2bf(v[3]);
  }
}

// ---------------- bias concat ----------------
__global__ __launch_bounds__(256) void concat_bias(const float* __restrict__ bq,
                                                   const float* __restrict__ bk,
                                                   const float* __restrict__ bv,
                                                   float* __restrict__ out) {
  const int i = blockIdx.x * 256 + threadIdx.x;   // grid 6 -> 1536
  float v = (i < 512) ? bq[i] : ((i < 1024) ? bk[i - 512] : bv[i - 1024]);
  out[i] = v;
}

// ---------------- transpose (+cast) to bf16: src [R][C] -> dst [C][R] ----------------
template <typename TI>
__global__ __launch_bounds__(256) void transpose_to_bf16(const TI* __restrict__ src,
                                                         unsigned short* __restrict__ dst,
                                                         int R, int C, int ldSrc, int ldDst,
                                                         long long sSrc, long long sDst) {
  __shared__ unsigned short tile[64][65];
  const TI* s = src + (size_t)blockIdx.z * (size_t)sSrc;
  unsigned short* d = dst + (size_t)blockIdx.z * (size_t)sDst;
  const int r0 = blockIdx.x * 64, c0 = blockIdx.y * 64;
  const int tc = threadIdx.x & 63, tg = threadIdx.x >> 6;
#pragma unroll
  for (int i = 0; i < 16; i++) {
    const int r = i * 4 + tg;
    TI v = s[(size_t)(r0 + r) * ldSrc + (c0 + tc)];
    unsigned short bits;
    if constexpr (sizeof(TI) == 4) bits = f2bf((float)v);
    else                           bits = (unsigned short)v;
    tile[r][tc] = bits;
  }
  __syncthreads();
#pragma unroll
  for (int i = 0; i < 16; i++) {
    const int rr = i * 4 + tg;
    d[(size_t)(c0 + rr) * ldDst + (r0 + tc)] = tile[tc][rr];
  }
}

// ---------------- combine: inv[k] = 1 / sum of partial colsums ----------------
__global__ __launch_bounds__(256) void stats_combine(const float* __restrict__ pl,
                                                     long long sPz,
                                                     float* __restrict__ inv,
                                                     long long sIz) {
  const size_t z = blockIdx.z;
  const int col = blockIdx.x * 256 + threadIdx.x;
  float L = 0.f;
#pragma unroll
  for (int mb = 0; mb < 16; mb++)
    L += pl[z * (size_t)sPz + (size_t)mb * T_ + col];
  inv[z * (size_t)sIz + col] = 1.0f / L;
}

// ---------------- scale Vt rows: Vt[d][k] *= inv[k] ----------------
__global__ __launch_bounds__(256) void scale_vt(unsigned short* __restrict__ Vt,
                                                long long sVz,
                                                const float* __restrict__ inv,
                                                long long sIz) {
  const size_t z = blockIdx.z;
  unsigned short* Vb = Vt + z * (size_t)sVz;
  const float* iv = inv + z * (size_t)sIz;
  const int idx = (blockIdx.x * 256 + threadIdx.x) * 8;  // grid.x=512 -> 512*2048
  const int k = idx & (T_ - 1);
  short8 v = *(const short8*)(Vb + idx);
  float4v i0 = *(const float4v*)(iv + k);
  float4v i1 = *(const float4v*)(iv + k + 4);
  short8 o;
#pragma unroll
  for (int j = 0; j < 8; j++) {
    float s = (j < 4) ? i0[j & 3] : i1[j & 3];
    o[j] = (short)f2bf(bf2f((unsigned short)v[j]) * s);
  }
  *(short8*)(Vb + idx) = o;
}

// ---------------- unified GEMM: C = A * B'^T  (BK=32, 32x32x16 MFMA) ----------------
// A [M][K] bf16 row-major (lda), B' [N][K] bf16 row-major (ldb), k-contiguous.
// MODE 0: bias add, bf16 out                        (QKV conv GEMM)
// MODE 1: P_raw = exp(v*scale-16) bf16 out + colsum (scores)
// MODE 2: plain, fp32 out                           (ctx)
// All modes: 128x128 block tile.
template <int MODE>
__global__ __launch_bounds__(256, 4)
void gemm_bt(const unsigned short* __restrict__ A, long long sAz, int lda,
             const unsigned short* __restrict__ Bm, long long sBz, int ldb,
             void* __restrict__ Out, long long sOz, int ldo,
             const float* __restrict__ bias,
             float* __restrict__ pl, long long sPz,
             int Kdim, float scale) {
  __shared__ unsigned short At[128 * 32];
  __shared__ unsigned short Bt[128 * 32];
  const int tid = threadIdx.x;
  const int lane = tid & 63;
  const int wave = tid >> 6;
  const int wm = wave >> 1, wn = wave & 1;
  const size_t z = blockIdx.z;
  const unsigned short* Ab = A + z * (size_t)sAz;
  const unsigned short* Bb = Bm + z * (size_t)sBz;
  const int m0 = blockIdx.x * 128, n0 = blockIdx.y * 128;

  float16v acc[2][2];
#pragma unroll
  for (int mi = 0; mi < 2; mi++)
#pragma unroll
    for (int nj = 0; nj < 2; nj++)
#pragma unroll
      for (int r = 0; r < 16; r++) acc[mi][nj][r] = 0.f;

  // staging lane map: lane -> row rloc=lane>>2 (of 16), stored chunk qs=lane&3,
  // fetched global chunk = qs ^ ((row>>1)&3)  (rows r, r+16 share the swizzle).
  const int rloc = lane >> 2, qs = lane & 3;
  const int rA = wave * 32 + rloc;
  const int qgA = qs ^ ((rA >> 1) & 3);
  const unsigned short* gA0 = Ab + (size_t)(m0 + rA) * lda + qgA * 8;
  const unsigned short* gA1 = gA0 + (size_t)16 * lda;
  unsigned short* lA0 = At + wave * 1024;
  unsigned short* lA1 = lA0 + 512;

  const unsigned short* gB0 = Bb + (size_t)(n0 + rA) * ldb + qgA * 8;
  const unsigned short* gB1 = gB0 + (size_t)16 * ldb;
  unsigned short* lB0 = Bt + wave * 1024;
  unsigned short* lB1 = lB0 + 512;

  // fragment read addressing: A/B operand [row = lane&31][k = (lane>>5)*8 + j]
  const int l31 = lane & 31;
  const int hi  = lane >> 5;
  int ar[2], br[2];
#pragma unroll
  for (int mi = 0; mi < 2; mi++) ar[mi] = wm * 64 + mi * 32 + l31;
#pragma unroll
  for (int nj = 0; nj < 2; nj++) br[nj] = wn * 64 + nj * 32 + l31;

  for (int kk = 0; kk < Kdim; kk += 32) {
    gld16(gA0, lA0);
    gld16(gA1, lA1);
    gld16(gB0, lB0);
    gld16(gB1, lB1);
    __syncthreads();

    // per-h fragment reads keep live frag regs at 4x short8 (16 VGPRs)
#pragma unroll
    for (int h = 0; h < 2; h++) {
      const int qlog = h * 2 + hi;
      short8 af[2], bfr[2];
#pragma unroll
      for (int mi = 0; mi < 2; mi++) {
        const int q = qlog ^ ((ar[mi] >> 1) & 3);
        af[mi] = *(const short8*)&At[ar[mi] * 32 + q * 8];
      }
#pragma unroll
      for (int nj = 0; nj < 2; nj++) {
        const int q = qlog ^ ((br[nj] >> 1) & 3);
        bfr[nj] = *(const short8*)&Bt[br[nj] * 32 + q * 8];
      }
#pragma unroll
      for (int mi = 0; mi < 2; mi++)
#pragma unroll
        for (int nj = 0; nj < 2; nj++)
          acc[mi][nj] = __builtin_amdgcn_mfma_f32_32x32x16_bf16(
              af[mi], bfr[nj], acc[mi][nj], 0, 0, 0);
    }
    __syncthreads();

    gA0 += 32; gA1 += 32; gB0 += 32; gB1 += 32;
  }

  // epilogue: C/D col = lane&31, row = (reg&3) + 8*(reg>>2) + 4*(lane>>5)
  float cs[2] = {0.f, 0.f};
#pragma unroll
  for (int mi = 0; mi < 2; mi++) {
#pragma unroll
    for (int nj = 0; nj < 2; nj++) {
      const int col = n0 + wn * 64 + nj * 32 + l31;
      float badd = 0.f;
      if constexpr (MODE == 0) badd = bias[col];
#pragma unroll
      for (int reg = 0; reg < 16; reg++) {
        const int row = m0 + wm * 64 + mi * 32 + (reg & 3) + 8 * (reg >> 2) + 4 * hi;
        float v = acc[mi][nj][reg] * scale + badd;
        if constexpr (MODE == 2) {
          ((float*)Out)[z * (size_t)sOz + (size_t)row * ldo + col] = v;
        } else if constexpr (MODE == 1) {
          float e = __expf(v - 16.f);          // fixed shift; |v| <~ 25
          cs[nj] += e;
          ((unsigned short*)Out)[z * (size_t)sOz + (size_t)row * ldo + col] = f2bf(e);
        } else {
          ((unsigned short*)Out)[z * (size_t)sOz + (size_t)row * ldo + col] = f2bf(v);
        }
      }
    }
  }
  if constexpr (MODE == 1) {
    // column sums: lane & lane^32 cover all 32 rows of a subtile -> xor-32;
    // then reduce the wm pair via LDS (At is free now).
#pragma unroll
    for (int nj = 0; nj < 2; nj++) cs[nj] += __shfl_xor(cs[nj], 32, 64);
    float* red = (float*)At;
    if (wm == 1 && hi == 0) {
#pragma unroll
      for (int nj = 0; nj < 2; nj++) red[wn * 64 + nj * 32 + l31] = cs[nj];
    }
    __syncthreads();
    if (wm == 0 && hi == 0) {
#pragma unroll
      for (int nj = 0; nj < 2; nj++) {
        const int c = wn * 64 + nj * 32 + l31;
        pl[z * (size_t)sPz + (size_t)blockIdx.x * T_ + (n0 + c)] = cs[nj] + red[c];
      }
    }
  }
}

// ---------------- host ----------------
extern "C" void kernel_launch(void* const* d_in, const int* in_sizes, int n_in,
                              void* d_out, int out_size, void* d_ws, size_t ws_size,
                              hipStream_t stream) {
  const float* x  = (const float*)d_in[0];
  const float* Wq = (const float*)d_in[1];
  const float* bq = (const float*)d_in[2];
  const float* Wk = (const float*)d_in[3];
  const float* bk = (const float*)d_in[4];
  const float* Wv = (const float*)d_in[5];
  const float* bv = (const float*)d_in[6];

  char* ws = (char*)d_ws;
  auto alloc = [&](size_t bytes) {
    char* p = ws; ws += (bytes + 255) & ~(size_t)255; return p;
  };
  unsigned short* xpad = (unsigned short*)alloc((size_t)B_ * TPAD_ * D_ * 2);
  unsigned short* Wt   = (unsigned short*)alloc((size_t)KC_ * KC_ * 2);     // [1536 u][1536 k]
  float*          bcat = (float*)alloc((size_t)KC_ * 4);
  unsigned short* QKV  = (unsigned short*)alloc((size_t)B_ * T_ * KC_ * 2); // [B][T][1536]
  unsigned short* Vt   = (unsigned short*)alloc((size_t)B_ * D_ * T_ * 2);
  float* invb = (float*)alloc((size_t)B_ * T_ * 4);
  float* pl   = (float*)alloc((size_t)B_ * 16 * T_ * 4);
  size_t used = (size_t)(ws - (char*)d_ws);
  const size_t sAll = (size_t)B_ * T_ * T_ * 2;   // bf16 P, all batches
  const size_t sOne = (size_t)T_ * T_ * 2;
  const int NB = (used + sAll <= ws_size) ? B_ : 1;  // ws-adaptive batching
  unsigned short* Sb = (unsigned short*)alloc(NB == B_ ? sAll : sOne);

  prep_x<<<dim3(1025, B_), 256, 0, stream>>>(x, xpad);
  concat_bias<<<dim3(6), 256, 0, stream>>>(bq, bk, bv, bcat);

  // Wq/Wk/Wv [1536][512] fp32 -> Wt rows [w*512 .. w*512+511], row length 1536
  const float* Ws[3] = {Wq, Wk, Wv};
  for (int w = 0; w < 3; w++)
    transpose_to_bf16<float><<<dim3(24, 8, 1), 256, 0, stream>>>(
        Ws[w], Wt + (size_t)w * D_ * KC_, KC_, D_, D_, KC_, 0, 0);

  // one QKV GEMM: M=2048/batch, N=1536, K=1536
  gemm_bt<0><<<dim3(16, 12, B_), 256, 0, stream>>>(
      xpad, (long long)TPAD_ * D_, D_,
      Wt, 0, KC_,
      QKV, (long long)T_ * KC_, KC_,
      bcat, nullptr, 0, KC_, 1.0f);

  // V slice [T][512] (row stride 1536) -> Vt [512][2048]
  transpose_to_bf16<unsigned short><<<dim3(32, 8, B_), 256, 0, stream>>>(
      QKV + 2 * D_, Vt, T_, D_, KC_, T_,
      (long long)T_ * KC_, (long long)D_ * T_);

  const float scale = 0.044194173824159216f;  // 1/sqrt(512)
  for (int b0 = 0; b0 < B_; b0 += NB) {
    const unsigned short* Qp = QKV + (size_t)b0 * T_ * KC_;          // +0
    const unsigned short* Kp = QKV + (size_t)b0 * T_ * KC_ + D_;     // +512
    // P_raw = exp(S-16) + partial column sums
    gemm_bt<1><<<dim3(16, 16, NB), 256, 0, stream>>>(
        Qp, (long long)T_ * KC_, KC_,
        Kp, (long long)T_ * KC_, KC_,
        Sb, (long long)T_ * T_, T_,
        nullptr, pl + (size_t)b0 * 16 * T_, (long long)16 * T_,
        D_, scale);
    stats_combine<<<dim3(8, 1, NB), 256, 0, stream>>>(
        pl + (size_t)b0 * 16 * T_, (long long)16 * T_,
        invb + (size_t)b0 * T_, T_);
    scale_vt<<<dim3(512, 1, NB), 256, 0, stream>>>(
        Vt + (size_t)b0 * D_ * T_, (long long)D_ * T_,
        invb + (size_t)b0 * T_, T_);
    // ctx: out = P_raw @ Vt'^T, 128x128 tiles (N=512 -> 4 n-blocks)
    gemm_bt<2><<<dim3(16, 4, NB), 256, 0, stream>>>(
        Sb, (long long)T_ * T_, T_,
        Vt + (size_t)b0 * D_ * T_, (long long)D_ * T_, T_,
        (float*)d_out + (size_t)b0 * T_ * D_, (long long)T_ * D_, D_,
        nullptr, nullptr, 0, T_, 1.0f);
  }
}

// Round 7
// 323.237 us; speedup vs baseline: 1.0449x; 1.0025x over previous
//
#include <hip/hip_runtime.h>

// Conv_Attention: q,k,v = causal_conv1d(x, W*) ; S = qk^T/sqrt(U);
// softmax over QUERY axis (per-column of S); out = P @ v.
// B=8, T=2048, Cin=U=512, K=3.
//
// Round 7 structure:
//  1. prep_x: x fp32 -> xpad bf16 [B][T+2][512]  (conv == GEMM)
//  2. transpose_w3: ONE launch, z=3 -> Wt_all [1536 u][1536 k] bf16
//  3. ONE QKV GEMM (N=1536) -> QKV bf16 [B][2048][1536]
//  4. transpose V slice -> Vt bf16 [B][512][2048]
//  5. scores GEMM: epilogue stores P_raw = bf16(exp(S*scale-16)) + partial colsums
//  6. stats_combine: inv[k] = 1/L[k]
//  7. scale_vt: Vt[d][k] *= inv[k]
//  8. ctx GEMM 64x128 tiles (1024 blocks, 12KB LDS, 32-AGPR acc) -> out fp32
//
// GEMM core: 32x32x16 MFMA, BK=32, global_load_lds width=16 staging, XOR
// chunk swizzle (q ^= (row>>1)&3). Plain __launch_bounds__(256): R6's (256,4)
// forced VGPR to 52 but occupancy stayed 30% and QKV regressed 115->120 µs —
// the K-loop is barrier-drain bound (m97 plateau), not occupancy bound.

#define B_   8
#define T_   2048
#define D_   512
#define KC_  1536
#define TPAD_ 2050

using short8   = __attribute__((ext_vector_type(8))) short;
using float4v  = __attribute__((ext_vector_type(4))) float;
using float16v = __attribute__((ext_vector_type(16))) float;

__device__ __forceinline__ float bf2f(unsigned short b) {
  unsigned u = ((unsigned)b) << 16;
  float f; __builtin_memcpy(&f, &u, 4); return f;
}
__device__ __forceinline__ unsigned short f2bf(float f) {
  unsigned u; __builtin_memcpy(&u, &f, 4);
  u += 0x7fffu + ((u >> 16) & 1u);          // RNE (finite inputs only)
  return (unsigned short)(u >> 16);
}

__device__ __forceinline__ void gld16(const void* g, void* l) {
  __builtin_amdgcn_global_load_lds((__attribute__((address_space(1))) void*)g,
                                   (__attribute__((address_space(3))) void*)l,
                                   16, 0, 0);
}

// ---------------- prep: pad + cast x ----------------
__global__ __launch_bounds__(256) void prep_x(const float* __restrict__ x,
                                              unsigned short* __restrict__ xpad) {
  const int b = blockIdx.y;
  const int i = (blockIdx.x * 256 + threadIdx.x) * 4;   // grid.x=1025 -> exactly 2050*512
  const int t = i >> 9;
  unsigned short* dst = xpad + (size_t)b * (TPAD_ * D_) + i;
  if (t < 2) {
    dst[0] = 0; dst[1] = 0; dst[2] = 0; dst[3] = 0;
  } else {
    const float* sp = x + ((size_t)b * T_ + (t - 2)) * D_ + (i & 511);
    float4v v = *(const float4v*)sp;
    dst[0] = f2bf(v[0]); dst[1] = f2bf(v[1]); dst[2] = f2bf(v[2]); dst[3] = f2bf(v[3]);
  }
}

// ---------------- bias concat ----------------
__global__ __launch_bounds__(256) void concat_bias(const float* __restrict__ bq,
                                                   const float* __restrict__ bk,
                                                   const float* __restrict__ bv,
                                                   float* __restrict__ out) {
  const int i = blockIdx.x * 256 + threadIdx.x;   // grid 6 -> 1536
  float v = (i < 512) ? bq[i] : ((i < 1024) ? bk[i - 512] : bv[i - 1024]);
  out[i] = v;
}

// ---------------- W transpose, all three in one launch (z picks source) ----------------
// Wsrc [1536=K*Cin rows][512 u] fp32 -> Wt rows [z*512+u][1536 k] bf16
__global__ __launch_bounds__(256) void transpose_w3(const float* __restrict__ Wq,
                                                    const float* __restrict__ Wk,
                                                    const float* __restrict__ Wv,
                                                    unsigned short* __restrict__ Wt) {
  __shared__ unsigned short tile[64][65];
  const float* s = (blockIdx.z == 0) ? Wq : (blockIdx.z == 1) ? Wk : Wv;
  unsigned short* d = Wt + (size_t)blockIdx.z * D_ * KC_;
  const int r0 = blockIdx.x * 64, c0 = blockIdx.y * 64;   // r: 0..1536 (k), c: 0..512 (u)
  const int tc = threadIdx.x & 63, tg = threadIdx.x >> 6;
#pragma unroll
  for (int i = 0; i < 16; i++) {
    const int r = i * 4 + tg;
    tile[r][tc] = f2bf(s[(size_t)(r0 + r) * D_ + (c0 + tc)]);
  }
  __syncthreads();
#pragma unroll
  for (int i = 0; i < 16; i++) {
    const int rr = i * 4 + tg;
    d[(size_t)(c0 + rr) * KC_ + (r0 + tc)] = tile[tc][rr];
  }
}

// ---------------- V transpose: QKV V-slice [T][512] (ld 1536) -> Vt [512][2048] ----------------
__global__ __launch_bounds__(256) void transpose_v(const unsigned short* __restrict__ src,
                                                   unsigned short* __restrict__ dst) {
  __shared__ unsigned short tile[64][65];
  const unsigned short* s = src + (size_t)blockIdx.z * T_ * KC_;
  unsigned short* d = dst + (size_t)blockIdx.z * D_ * T_;
  const int r0 = blockIdx.x * 64, c0 = blockIdx.y * 64;   // r: t-dim, c: d-dim
  const int tc = threadIdx.x & 63, tg = threadIdx.x >> 6;
#pragma unroll
  for (int i = 0; i < 16; i++) {
    const int r = i * 4 + tg;
    tile[r][tc] = s[(size_t)(r0 + r) * KC_ + (c0 + tc)];
  }
  __syncthreads();
#pragma unroll
  for (int i = 0; i < 16; i++) {
    const int rr = i * 4 + tg;
    d[(size_t)(c0 + rr) * T_ + (r0 + tc)] = tile[tc][rr];
  }
}

// ---------------- combine: inv[k] = 1 / sum of partial colsums ----------------
__global__ __launch_bounds__(256) void stats_combine(const float* __restrict__ pl,
                                                     long long sPz,
                                                     float* __restrict__ inv,
                                                     long long sIz) {
  const size_t z = blockIdx.z;
  const int col = blockIdx.x * 256 + threadIdx.x;
  float L = 0.f;
#pragma unroll
  for (int mb = 0; mb < 16; mb++)
    L += pl[z * (size_t)sPz + (size_t)mb * T_ + col];
  inv[z * (size_t)sIz + col] = 1.0f / L;
}

// ---------------- scale Vt rows: Vt[d][k] *= inv[k] ----------------
__global__ __launch_bounds__(256) void scale_vt(unsigned short* __restrict__ Vt,
                                                long long sVz,
                                                const float* __restrict__ inv,
                                                long long sIz) {
  const size_t z = blockIdx.z;
  unsigned short* Vb = Vt + z * (size_t)sVz;
  const float* iv = inv + z * (size_t)sIz;
  const int idx = (blockIdx.x * 256 + threadIdx.x) * 8;  // grid.x=512 -> 512*2048
  const int k = idx & (T_ - 1);
  short8 v = *(const short8*)(Vb + idx);
  float4v i0 = *(const float4v*)(iv + k);
  float4v i1 = *(const float4v*)(iv + k + 4);
  short8 o;
#pragma unroll
  for (int j = 0; j < 8; j++) {
    float s = (j < 4) ? i0[j & 3] : i1[j & 3];
    o[j] = (short)f2bf(bf2f((unsigned short)v[j]) * s);
  }
  *(short8*)(Vb + idx) = o;
}

// ---------------- unified GEMM: C = A * B'^T  (BK=32, 32x32x16 MFMA) ----------------
// A [M][K] bf16 row-major (lda), B' [N][K] bf16 row-major (ldb), k-contiguous.
// MODE 0: bias add, bf16 out                        (QKV conv GEMM, 128x128)
// MODE 1: P_raw = exp(v*scale-16) bf16 out + colsum (scores,        128x128)
// MODE 2: plain, fp32 out                           (ctx,            64x128)
template <int MODE>
__global__ __launch_bounds__(256)
void gemm_bt(const unsigned short* __restrict__ A, long long sAz, int lda,
             const unsigned short* __restrict__ Bm, long long sBz, int ldb,
             void* __restrict__ Out, long long sOz, int ldo,
             const float* __restrict__ bias,
             float* __restrict__ pl, long long sPz,
             int Kdim, float scale) {
  constexpr int MI = (MODE == 2) ? 1 : 2;   // 32-row subtiles per wave
  constexpr int BM = MI * 64;               // block m-extent (64 or 128)
  __shared__ unsigned short At[BM * 32];
  __shared__ unsigned short Bt[128 * 32];
  const int tid = threadIdx.x;
  const int lane = tid & 63;
  const int wave = tid >> 6;
  const int wm = wave >> 1, wn = wave & 1;
  const size_t z = blockIdx.z;
  const unsigned short* Ab = A + z * (size_t)sAz;
  const unsigned short* Bb = Bm + z * (size_t)sBz;
  const int m0 = blockIdx.x * BM, n0 = blockIdx.y * 128;

  float16v acc[MI][2];
#pragma unroll
  for (int mi = 0; mi < MI; mi++)
#pragma unroll
    for (int nj = 0; nj < 2; nj++)
#pragma unroll
      for (int r = 0; r < 16; r++) acc[mi][nj][r] = 0.f;

  // staging lane map: lane -> row rloc=lane>>2 (of 16), stored chunk qs=lane&3,
  // fetched global chunk = qs ^ ((row>>1)&3).
  const int rloc = lane >> 2, qs = lane & 3;
  // A: BM rows -> BM/16 gld16 instrs; wave w covers rows w*(BM/4*16/16)...
  const int rA = (MI == 2) ? (wave * 32 + rloc) : (wave * 16 + rloc);
  const int qgA = qs ^ ((rA >> 1) & 3);
  const unsigned short* gA0 = Ab + (size_t)(m0 + rA) * lda + qgA * 8;
  const unsigned short* gA1 = gA0 + (size_t)16 * lda;   // MI==2 only
  unsigned short* lA0 = At + ((MI == 2) ? wave * 1024 : wave * 512);
  unsigned short* lA1 = lA0 + 512;

  const int rB = wave * 32 + rloc;
  const int qgB = qs ^ ((rB >> 1) & 3);
  const unsigned short* gB0 = Bb + (size_t)(n0 + rB) * ldb + qgB * 8;
  const unsigned short* gB1 = gB0 + (size_t)16 * ldb;
  unsigned short* lB0 = Bt + wave * 1024;
  unsigned short* lB1 = lB0 + 512;

  // fragment read addressing: A/B operand [row = lane&31][k = (lane>>5)*8 + j]
  const int l31 = lane & 31;
  const int hi  = lane >> 5;
  int ar[MI], br[2];
#pragma unroll
  for (int mi = 0; mi < MI; mi++) ar[mi] = wm * (MI * 32) + mi * 32 + l31;
#pragma unroll
  for (int nj = 0; nj < 2; nj++) br[nj] = wn * 64 + nj * 32 + l31;

  for (int kk = 0; kk < Kdim; kk += 32) {
    gld16(gA0, lA0);
    if constexpr (MI == 2) gld16(gA1, lA1);
    gld16(gB0, lB0);
    gld16(gB1, lB1);
    __syncthreads();

#pragma unroll
    for (int h = 0; h < 2; h++) {
      const int qlog = h * 2 + hi;
      short8 af[MI], bfr[2];
#pragma unroll
      for (int mi = 0; mi < MI; mi++) {
        const int q = qlog ^ ((ar[mi] >> 1) & 3);
        af[mi] = *(const short8*)&At[ar[mi] * 32 + q * 8];
      }
#pragma unroll
      for (int nj = 0; nj < 2; nj++) {
        const int q = qlog ^ ((br[nj] >> 1) & 3);
        bfr[nj] = *(const short8*)&Bt[br[nj] * 32 + q * 8];
      }
#pragma unroll
      for (int mi = 0; mi < MI; mi++)
#pragma unroll
        for (int nj = 0; nj < 2; nj++)
          acc[mi][nj] = __builtin_amdgcn_mfma_f32_32x32x16_bf16(
              af[mi], bfr[nj], acc[mi][nj], 0, 0, 0);
    }
    __syncthreads();

    gA0 += 32; gB0 += 32; gB1 += 32;
    if constexpr (MI == 2) gA1 += 32;
  }

  // epilogue: C/D col = lane&31, row = (reg&3) + 8*(reg>>2) + 4*(lane>>5)
  float cs[2] = {0.f, 0.f};
#pragma unroll
  for (int mi = 0; mi < MI; mi++) {
#pragma unroll
    for (int nj = 0; nj < 2; nj++) {
      const int col = n0 + wn * 64 + nj * 32 + l31;
      float badd = 0.f;
      if constexpr (MODE == 0) badd = bias[col];
#pragma unroll
      for (int reg = 0; reg < 16; reg++) {
        const int row = m0 + wm * (MI * 32) + mi * 32 + (reg & 3) + 8 * (reg >> 2) + 4 * hi;
        float v = acc[mi][nj][reg] * scale + badd;
        if constexpr (MODE == 2) {
          ((float*)Out)[z * (size_t)sOz + (size_t)row * ldo + col] = v;
        } else if constexpr (MODE == 1) {
          float e = __expf(v - 16.f);          // fixed shift; |v| <~ 25
          cs[nj] += e;
          ((unsigned short*)Out)[z * (size_t)sOz + (size_t)row * ldo + col] = f2bf(e);
        } else {
          ((unsigned short*)Out)[z * (size_t)sOz + (size_t)row * ldo + col] = f2bf(v);
        }
      }
    }
  }
  if constexpr (MODE == 1) {
    // column sums: xor-32 covers the 32 rows of a subtile; wm pair via LDS.
#pragma unroll
    for (int nj = 0; nj < 2; nj++) cs[nj] += __shfl_xor(cs[nj], 32, 64);
    float* red = (float*)At;
    if (wm == 1 && hi == 0) {
#pragma unroll
      for (int nj = 0; nj < 2; nj++) red[wn * 64 + nj * 32 + l31] = cs[nj];
    }
    __syncthreads();
    if (wm == 0 && hi == 0) {
#pragma unroll
      for (int nj = 0; nj < 2; nj++) {
        const int c = wn * 64 + nj * 32 + l31;
        pl[z * (size_t)sPz + (size_t)blockIdx.x * T_ + (n0 + c)] = cs[nj] + red[c];
      }
    }
  }
}

// ---------------- host ----------------
extern "C" void kernel_launch(void* const* d_in, const int* in_sizes, int n_in,
                              void* d_out, int out_size, void* d_ws, size_t ws_size,
                              hipStream_t stream) {
  const float* x  = (const float*)d_in[0];
  const float* Wq = (const float*)d_in[1];
  const float* bq = (const float*)d_in[2];
  const float* Wk = (const float*)d_in[3];
  const float* bk = (const float*)d_in[4];
  const float* Wv = (const float*)d_in[5];
  const float* bv = (const float*)d_in[6];

  char* ws = (char*)d_ws;
  auto alloc = [&](size_t bytes) {
    char* p = ws; ws += (bytes + 255) & ~(size_t)255; return p;
  };
  unsigned short* xpad = (unsigned short*)alloc((size_t)B_ * TPAD_ * D_ * 2);
  unsigned short* Wt   = (unsigned short*)alloc((size_t)KC_ * KC_ * 2);     // [1536 u][1536 k]
  float*          bcat = (float*)alloc((size_t)KC_ * 4);
  unsigned short* QKV  = (unsigned short*)alloc((size_t)B_ * T_ * KC_ * 2); // [B][T][1536]
  unsigned short* Vt   = (unsigned short*)alloc((size_t)B_ * D_ * T_ * 2);
  float* invb = (float*)alloc((size_t)B_ * T_ * 4);
  float* pl   = (float*)alloc((size_t)B_ * 16 * T_ * 4);
  size_t used = (size_t)(ws - (char*)d_ws);
  const size_t sAll = (size_t)B_ * T_ * T_ * 2;   // bf16 P, all batches
  const size_t sOne = (size_t)T_ * T_ * 2;
  const int NB = (used + sAll <= ws_size) ? B_ : 1;  // ws-adaptive batching
  unsigned short* Sb = (unsigned short*)alloc(NB == B_ ? sAll : sOne);

  prep_x<<<dim3(1025, B_), 256, 0, stream>>>(x, xpad);
  concat_bias<<<dim3(6), 256, 0, stream>>>(bq, bk, bv, bcat);
  transpose_w3<<<dim3(24, 8, 3), 256, 0, stream>>>(Wq, Wk, Wv, Wt);

  // one QKV GEMM: M=2048/batch, N=1536, K=1536
  gemm_bt<0><<<dim3(16, 12, B_), 256, 0, stream>>>(
      xpad, (long long)TPAD_ * D_, D_,
      Wt, 0, KC_,
      QKV, (long long)T_ * KC_, KC_,
      bcat, nullptr, 0, KC_, 1.0f);

  // V slice [T][512] (row stride 1536) -> Vt [512][2048]
  transpose_v<<<dim3(32, 8, B_), 256, 0, stream>>>(QKV + 2 * D_, Vt);

  const float scale = 0.044194173824159216f;  // 1/sqrt(512)
  for (int b0 = 0; b0 < B_; b0 += NB) {
    const unsigned short* Qp = QKV + (size_t)b0 * T_ * KC_;          // +0
    const unsigned short* Kp = QKV + (size_t)b0 * T_ * KC_ + D_;     // +512
    // P_raw = exp(S-16) + partial column sums
    gemm_bt<1><<<dim3(16, 16, NB), 256, 0, stream>>>(
        Qp, (long long)T_ * KC_, KC_,
        Kp, (long long)T_ * KC_, KC_,
        Sb, (long long)T_ * T_, T_,
        nullptr, pl + (size_t)b0 * 16 * T_, (long long)16 * T_,
        D_, scale);
    stats_combine<<<dim3(8, 1, NB), 256, 0, stream>>>(
        pl + (size_t)b0 * 16 * T_, (long long)16 * T_,
        invb + (size_t)b0 * T_, T_);
    scale_vt<<<dim3(512, 1, NB), 256, 0, stream>>>(
        Vt + (size_t)b0 * D_ * T_, (long long)D_ * T_,
        invb + (size_t)b0 * T_, T_);
    // ctx: out = P_raw @ Vt'^T, 64x128 tiles (32 m-blocks x 4 n-blocks)
    gemm_bt<2><<<dim3(32, 4, NB), 256, 0, stream>>>(
        Sb, (long long)T_ * T_, T_,
        Vt + (size_t)b0 * D_ * T_, (long long)D_ * T_, T_,
        (float*)d_out + (size_t)b0 * T_ * D_, (long long)T_ * D_, D_,
        nullptr, nullptr, 0, T_, 1.0f);
  }
}